// Round 4
// baseline (1940.245 us; speedup 1.0000x reference)
//
#include <hip/hip_runtime.h>

#define NNODES 40000
#define NEDGE  640000
#define NBUCK  625          // buckets per sign, 64 rows each (625*64 = 40000)
#define ECAP   1408         // per-bucket capacity (mean 1024, sd 32 -> 12 sigma pad)

typedef __attribute__((ext_vector_type(8))) short bfrag;
typedef __attribute__((ext_vector_type(4))) float facc;

__device__ inline ushort f2bf(float f) {
    uint u = __float_as_uint(f);
    return (ushort)((u + 0x7FFFu + ((u >> 16) & 1u)) >> 16);
}
__device__ inline float bf2f(ushort h) {
    return __uint_as_float(((uint)h) << 16);
}

// ---------------- edge partition into 64-row buckets ----------------
// 80 blocks x 16384-edge chunks, 2-pass: LDS histogram -> per-bucket global
// reservation -> direct scatter (runs of ~13 contiguous entries => single-XCD
// line ownership, ~1.5x write amplification instead of 8x).

__global__ __launch_bounds__(256) void partition_k(const int* __restrict__ pos_idx,
                                                   const float* __restrict__ pos_w,
                                                   const int* __restrict__ neg_idx,
                                                   const float* __restrict__ neg_w,
                                                   int* __restrict__ ecnt,
                                                   int2* __restrict__ edges) {
    __shared__ int lhist[2 * NBUCK];
    __shared__ int lbase[2 * NBUCK];
    long g0 = (long)blockIdx.x * 16384;
    for (int i = threadIdx.x; i < 2 * NBUCK; i += 256) lhist[i] = 0;
    __syncthreads();
    for (int i = 0; i < 64; ++i) {
        long g = g0 + i * 256 + threadIdx.x;
        if (g < 2 * NEDGE) {
            int sign = g >= NEDGE;
            int e = (int)(g - (long)sign * NEDGE);
            int row = sign ? neg_idx[e] : pos_idx[e];
            atomicAdd(&lhist[sign * NBUCK + (row >> 6)], 1);
        }
    }
    __syncthreads();
    for (int b = threadIdx.x; b < 2 * NBUCK; b += 256) {
        int c = lhist[b];
        lbase[b] = c ? atomicAdd(&ecnt[b], c) : 0;
        lhist[b] = 0;
    }
    __syncthreads();
    for (int i = 0; i < 64; ++i) {
        long g = g0 + i * 256 + threadIdx.x;
        if (g < 2 * NEDGE) {
            int sign = g >= NEDGE;
            int e = (int)(g - (long)sign * NEDGE);
            int row = sign ? neg_idx[e] : pos_idx[e];
            int col = sign ? neg_idx[NEDGE + e] : pos_idx[NEDGE + e];
            float wv = sign ? neg_w[e] : pos_w[e];
            int b = sign * NBUCK + (row >> 6);
            int off = lbase[b] + atomicAdd(&lhist[b], 1);
            if (off < ECAP)
                edges[(long)b * ECAP + off] =
                    make_int2((int)((uint)col | ((uint)(row & 63) << 16)), __float_as_int(wv));
        }
    }
}

// ---------------- fp32 -> bf16 conversion ----------------

__global__ __launch_bounds__(256) void cvt_bf16_k(const float* __restrict__ in,
                                                  ushort* __restrict__ out, int n8) {
    int i = blockIdx.x * 256 + threadIdx.x;
    if (i >= n8) return;
    const float4* p = (const float4*)(in + (long)i * 8);
    float4 a = p[0], b = p[1];
    uint4 o;
    o.x = (uint)f2bf(a.x) | ((uint)f2bf(a.y) << 16);
    o.y = (uint)f2bf(a.z) | ((uint)f2bf(a.w) << 16);
    o.z = (uint)f2bf(b.x) | ((uint)f2bf(b.y) << 16);
    o.w = (uint)f2bf(b.z) | ((uint)f2bf(b.w) << 16);
    ((uint4*)out)[i] = o;
}

// ---------------- pack all W into MFMA B-fragment order ----------------

__global__ __launch_bounds__(256) void pack_all_k(const float* __restrict__ Wo,
                                                  const float* __restrict__ Wp,
                                                  const float* __restrict__ Wn,
                                                  const float* __restrict__ Wm,
                                                  ushort* __restrict__ out) {
    int idx = blockIdx.x * 256 + threadIdx.x;      // 0..98303
    const float* W;
    ushort* dst;
    int local;
    if (idx < 49152) {
        int m = idx >> 14;
        local = idx & 16383;
        W = (m == 0) ? Wo : (m == 1) ? Wp : Wn;
        dst = out + m * 16384;
    } else {
        local = idx - 49152;
        W = Wm;
        dst = out + 49152;
    }
    int j = local & 7, l = (local >> 3) & 63, t = (local >> 9) & 7, ks = local >> 12;
    int k = ks * 32 + (l >> 4) * 8 + j;
    int c = (l & 15) + 16 * t;
    dst[local] = f2bf(W[k * 128 + c]);
}

// ---------------- fused triple MFMA GEMM: xb @ {W_org,W_pos,W_neg} ----------------

__global__ __launch_bounds__(256) void mfma_gemm3_k(const ushort* __restrict__ A,
                                                    const ushort* __restrict__ B0,
                                                    const ushort* __restrict__ B1,
                                                    const ushort* __restrict__ B2,
                                                    ushort* __restrict__ O0,
                                                    ushort* __restrict__ O1,
                                                    ushort* __restrict__ O2) {
    int lane = threadIdx.x & 63, wave = threadIdx.x >> 6;
    long rbase = (long)blockIdx.x * 64 + wave * 16;
    int r = lane & 15, kg = lane >> 4;
    const bfrag* Ap = (const bfrag*)(A + (rbase + r) * 128 + kg * 8);
    bfrag a[4];
#pragma unroll
    for (int ks = 0; ks < 4; ++ks) a[ks] = Ap[ks * 4];
    const ushort* Bs[3] = {B0, B1, B2};
    ushort* Os[3] = {O0, O1, O2};
    long orow = rbase + kg * 4;
#pragma unroll
    for (int m = 0; m < 3; ++m) {
        const bfrag* Bq = (const bfrag*)Bs[m] + lane;
        facc acc[8];
#pragma unroll
        for (int t = 0; t < 8; ++t) acc[t] = (facc){0.f, 0.f, 0.f, 0.f};
#pragma unroll
        for (int ks = 0; ks < 4; ++ks)
#pragma unroll
            for (int t = 0; t < 8; ++t)
                acc[t] = __builtin_amdgcn_mfma_f32_16x16x32_bf16(a[ks], Bq[(ks * 8 + t) * 64], acc[t], 0, 0, 0);
        ushort* O = Os[m];
#pragma unroll
        for (int t = 0; t < 8; ++t)
#pragma unroll
            for (int j = 0; j < 4; ++j)
                O[(orow + j) * 128 + 16 * t + r] = f2bf(acc[t][j]);
    }
}

// ---------------- final MFMA GEMM K=384 + fused row-L2-normalize ----------------

__global__ __launch_bounds__(256) void mfma_gemm_mlp_k(const ushort* __restrict__ A,
                                                       const ushort* __restrict__ Bp,
                                                       float* __restrict__ Out) {
    int lane = threadIdx.x & 63, wave = threadIdx.x >> 6;
    long rbase = (long)blockIdx.x * 64 + wave * 16;
    int r = lane & 15, kg = lane >> 4;
    facc acc[8];
#pragma unroll
    for (int t = 0; t < 8; ++t) acc[t] = (facc){0.f, 0.f, 0.f, 0.f};
    const bfrag* Ap = (const bfrag*)(A + (rbase + r) * 384 + kg * 8);
    const bfrag* Bq = (const bfrag*)Bp + lane;
#pragma unroll
    for (int ks = 0; ks < 12; ++ks) {
        bfrag a = Ap[ks * 4];
#pragma unroll
        for (int t = 0; t < 8; ++t)
            acc[t] = __builtin_amdgcn_mfma_f32_16x16x32_bf16(a, Bq[(ks * 8 + t) * 64], acc[t], 0, 0, 0);
    }
    long orow = rbase + kg * 4;
#pragma unroll
    for (int j = 0; j < 4; ++j) {
        float ss = 0.f;
#pragma unroll
        for (int t = 0; t < 8; ++t) ss = fmaf(acc[t][j], acc[t][j], ss);
        ss += __shfl_xor(ss, 1);
        ss += __shfl_xor(ss, 2);
        ss += __shfl_xor(ss, 4);
        ss += __shfl_xor(ss, 8);
        float inv = 1.f / fmaxf(sqrtf(ss), 1e-12f);
#pragma unroll
        for (int t = 0; t < 8; ++t)
            Out[(orow + j) * 128 + 16 * t + r] = acc[t][j] * inv;
    }
}

// ---------------- bucketed-COO SpMM with LDS accumulator ----------------
// block = one 64-row bucket; acc[64][128] f32 in LDS (32 KB).
// PHASE 1: out = 2*A@in (bf16).  PHASE 2: out = 1.875*A@in - 1.6875*prev,
// plus fused per-channel batch stats on the rounded output.

#define PROC1(J) { \
    uint pu = (uint)__shfl(ed.x, (J)); \
    float wv = __int_as_float(__shfl(ed.y, (J))); \
    uint g = in[(pu & 0xFFFFu) * 64 + lane]; \
    uint rb = (pu >> 16) * 128 + 2u * lane; \
    atomicAdd(&acc[rb],     wv * __uint_as_float(g << 16)); \
    atomicAdd(&acc[rb + 1], wv * __uint_as_float(g & 0xFFFF0000u)); }

template<int PHASE>
__global__ __launch_bounds__(256) void spmmb_k(const int* __restrict__ ecnt,
                                               const int2* __restrict__ edges,
                                               const uint* __restrict__ in_pos,
                                               const uint* __restrict__ in_neg,
                                               const uint* __restrict__ prev_pos,
                                               const uint* __restrict__ prev_neg,
                                               uint* __restrict__ out_pos,
                                               uint* __restrict__ out_neg,
                                               float* __restrict__ sums,
                                               float* __restrict__ sumsq) {
    __shared__ float acc[64 * 128];
    int b = blockIdx.x;
    int sign = b >= NBUCK;
    int r0 = (b - sign * NBUCK) * 64;
    const uint* in = sign ? in_neg : in_pos;
    int tid = threadIdx.x, lane = tid & 63, wid = tid >> 6;
    for (int i = tid; i < 8192; i += 256) acc[i] = 0.f;
    __syncthreads();
    long e0 = (long)b * ECAP;
    int cnt = ecnt[b]; if (cnt > ECAP) cnt = ECAP;
    int nfull = cnt >> 6, rem = cnt & 63;
    for (int k = wid; k < nfull; k += 4) {
        int2 ed = edges[e0 + k * 64 + lane];
#pragma unroll
        for (int j = 0; j < 64; j += 4) {
            PROC1(j) PROC1(j + 1) PROC1(j + 2) PROC1(j + 3)
        }
    }
    if (rem && wid == (nfull & 3)) {
        int2 ed = (lane < rem) ? edges[e0 + nfull * 64 + lane] : make_int2(0, 0);
        for (int j = 0; j < rem; ++j) { PROC1(j) }
    }
    __syncthreads();
    int cp = tid & 63, rg = tid >> 6;
    const float2* accv = (const float2*)acc;
    uint* out = sign ? out_neg : out_pos;
    if (PHASE == 1) {
#pragma unroll
        for (int rr = 0; rr < 16; ++rr) {
            int r = rg * 16 + rr;
            float2 v = accv[r * 64 + cp];
            out[(long)(r0 + r) * 64 + cp] = (uint)f2bf(2.f * v.x) | ((uint)f2bf(2.f * v.y) << 16);
        }
    } else {
        const uint* prev = sign ? prev_neg : prev_pos;
        float s0 = 0.f, q0 = 0.f, s1 = 0.f, q1 = 0.f;
#pragma unroll
        for (int rr = 0; rr < 16; ++rr) {
            int r = rg * 16 + rr;
            float2 v = accv[r * 64 + cp];
            uint pu = prev[(long)(r0 + r) * 64 + cp];
            float rx = fmaf(1.875f, v.x, -1.6875f * __uint_as_float(pu << 16));
            float ry = fmaf(1.875f, v.y, -1.6875f * __uint_as_float(pu & 0xFFFF0000u));
            ushort bx = f2bf(rx), by = f2bf(ry);
            out[(long)(r0 + r) * 64 + cp] = (uint)bx | ((uint)by << 16);
            float fx = bf2f(bx), fy = bf2f(by);
            s0 += fx; q0 = fmaf(fx, fx, q0);
            s1 += fy; q1 = fmaf(fy, fy, q1);
        }
        __syncthreads();
        float* part = acc;
        part[tid] = s0; part[256 + tid] = q0; part[512 + tid] = s1; part[768 + tid] = q1;
        __syncthreads();
        if (tid < 64) {
            float a0 = part[tid] + part[tid + 64] + part[tid + 128] + part[tid + 192];
            float b0 = part[256 + tid] + part[320 + tid] + part[384 + tid] + part[448 + tid];
            float a1 = part[512 + tid] + part[576 + tid] + part[640 + tid] + part[704 + tid];
            float b1 = part[768 + tid] + part[832 + tid] + part[896 + tid] + part[960 + tid];
            int sb = 128 + sign * 128;
            atomicAdd(&sums[sb + 2 * tid], a0);
            atomicAdd(&sumsq[sb + 2 * tid], b0);
            atomicAdd(&sums[sb + 2 * tid + 1], a1);
            atomicAdd(&sumsq[sb + 2 * tid + 1], b1);
        }
    }
}

// ---------------- batch stats for org (bf16 input) ----------------

__global__ __launch_bounds__(256) void stats_k(const ushort* __restrict__ buf,
                                               float* __restrict__ sum,
                                               float* __restrict__ sumsq) {
    int c = threadIdx.x & 127, half = threadIdx.x >> 7;
    int r0 = blockIdx.x * 128;
    int rend = r0 + 128; if (rend > NNODES) rend = NNODES;
    float s = 0.f, s2 = 0.f;
    for (int r = r0 + half; r < rend; r += 2) {
        float v = bf2f(buf[(long)r * 128 + c]);
        s += v;
        s2 = fmaf(v, v, s2);
    }
    __shared__ float sh[256], sh2[256];
    sh[threadIdx.x] = s; sh2[threadIdx.x] = s2;
    __syncthreads();
    if (threadIdx.x < 128) {
        atomicAdd(&sum[c],   sh[c]  + sh[c + 128]);
        atomicAdd(&sumsq[c], sh2[c] + sh2[c + 128]);
    }
}

__global__ void bnfin_k(const float* __restrict__ sum, const float* __restrict__ sumsq,
                        const float* __restrict__ g0, const float* __restrict__ be0,
                        const float* __restrict__ g1, const float* __restrict__ be1,
                        const float* __restrict__ g2, const float* __restrict__ be2,
                        float* __restrict__ bn) {
    int i = threadIdx.x;
    if (i >= 384) return;
    int s = i >> 7, c = i & 127;
    float mean = sum[i] * (1.f / NNODES);
    float var  = sumsq[i] * (1.f / NNODES) - mean * mean;
    const float* g = (s == 0) ? g0 : (s == 1) ? g1 : g2;
    const float* b = (s == 0) ? be0 : (s == 1) ? be1 : be2;
    float sc = g[c] * rsqrtf(var + 1e-5f);
    bn[s * 256 + c]       = sc;
    bn[s * 256 + 128 + c] = b[c] - mean * sc;
}

// ---------------- BN + PReLU + concat -> bf16 [N x 384] ----------------

__global__ __launch_bounds__(256) void bn_concat_k(const ushort* __restrict__ org,
                                                   const ushort* __restrict__ pos,
                                                   const ushort* __restrict__ neg,
                                                   const float* __restrict__ bn,
                                                   const float* __restrict__ prelu_w,
                                                   ushort* __restrict__ cb) {
    int idx = blockIdx.x * 256 + threadIdx.x;     // 1,920,000 threads
    int r = idx / 48;
    int q = idx - r * 48;
    int s = q >> 4, w8 = q & 15;
    const ushort* src = (s == 0) ? org : (s == 1) ? pos : neg;
    float pw = prelu_w[0];
    int c0 = w8 * 8;
    uint4 u = *(const uint4*)(src + (long)r * 128 + c0);
    uint uu[4] = {u.x, u.y, u.z, u.w};
    uint oo[4];
#pragma unroll
    for (int k = 0; k < 4; ++k) {
        float vx = __uint_as_float(uu[k] << 16);
        float vy = __uint_as_float(uu[k] & 0xFFFF0000u);
        float scx = bn[s * 256 + c0 + 2 * k],       scy = bn[s * 256 + c0 + 2 * k + 1];
        float shx = bn[s * 256 + 128 + c0 + 2 * k], shy = bn[s * 256 + 128 + c0 + 2 * k + 1];
        float ox = fmaf(vx, scx, shx); ox = (ox >= 0.f) ? ox : pw * ox;
        float oy = fmaf(vy, scy, shy); oy = (oy >= 0.f) ? oy : pw * oy;
        oo[k] = (uint)f2bf(ox) | ((uint)f2bf(oy) << 16);
    }
    *(uint4*)(cb + (long)r * 384 + s * 128 + c0) = make_uint4(oo[0], oo[1], oo[2], oo[3]);
}

// ---------------- launch ----------------

extern "C" void kernel_launch(void* const* d_in, const int* in_sizes, int n_in,
                              void* d_out, int out_size, void* d_ws, size_t ws_size,
                              hipStream_t stream) {
    const float* x       = (const float*)d_in[0];
    const int*   pos_idx = (const int*)d_in[1];
    const float* pos_w   = (const float*)d_in[2];
    const int*   neg_idx = (const int*)d_in[3];
    const float* neg_w   = (const float*)d_in[4];
    const float* W_org   = (const float*)d_in[5];
    const float* W_pos   = (const float*)d_in[6];
    const float* W_neg   = (const float*)d_in[7];
    const float* g_org   = (const float*)d_in[8];
    const float* b_org   = (const float*)d_in[9];
    const float* g_pos   = (const float*)d_in[10];
    const float* b_pos   = (const float*)d_in[11];
    const float* g_neg   = (const float*)d_in[12];
    const float* b_neg   = (const float*)d_in[13];
    const float* prelu_w = (const float*)d_in[14];
    const float* W_mlp   = (const float*)d_in[15];
    float* out = (float*)d_out;

    char* ws = (char*)d_ws;
    const size_t FB = (size_t)NNODES * 128 * 2;       // 10,240,000 B
    ushort* org0b = (ushort*)(ws);
    ushort* p0b   = (ushort*)(ws + FB);
    ushort* n0b   = (ushort*)(ws + 2 * FB);
    ushort* xb    = (ushort*)(ws + 3 * FB);
    int2* edges   = (int2*)(ws + 4 * FB);             // 2*NBUCK*ECAP*8 = 14,080,000 B
    ushort* cb    = xb;                               // reuses xb+edges (dead by then), 30.72 MB
    char* small = ws + 61440000;
    int* ecnt    = (int*)small;                       // 2*NBUCK*4 = 5000 B (pad 5120)
    float* sums  = (float*)(small + 5120);            // 1536
    float* sumsq = (float*)(small + 5120 + 1536);     // 1536  (memset covers 0..8192)
    float* bn    = (float*)(small + 8192);            // 3072
    ushort* Wb   = (ushort*)(small + 8192 + 3072);    // 196,608 B
    uint* t1_pos = (uint*)d_out;                      // bf16 scratch in d_out (10.24 MB)
    uint* t1_neg = (uint*)d_out + NNODES * 64;        // second half (10.24 MB)

    hipMemsetAsync(small, 0, 8192, stream);

    partition_k<<<79, 256, 0, stream>>>(pos_idx, pos_w, neg_idx, neg_w, ecnt, edges);

    cvt_bf16_k<<<2500, 256, 0, stream>>>(x, xb, 640000);
    pack_all_k<<<384, 256, 0, stream>>>(W_org, W_pos, W_neg, W_mlp, Wb);

    mfma_gemm3_k<<<625, 256, 0, stream>>>(xb, Wb, Wb + 16384, Wb + 32768, org0b, p0b, n0b);
    stats_k<<<313, 256, 0, stream>>>(org0b, sums, sumsq);

    // Jacobi (a=b=1, K=3): x1 = 2*A@x0 ; x2 = 1.875*A@x1 - 1.6875*x0
    spmmb_k<1><<<2 * NBUCK, 256, 0, stream>>>(ecnt, edges,
        (const uint*)p0b, (const uint*)n0b, nullptr, nullptr, t1_pos, t1_neg, sums, sumsq);
    spmmb_k<2><<<2 * NBUCK, 256, 0, stream>>>(ecnt, edges,
        t1_pos, t1_neg, (const uint*)p0b, (const uint*)n0b, (uint*)p0b, (uint*)n0b, sums, sumsq);

    bnfin_k<<<1, 384, 0, stream>>>(sums, sumsq, g_org, b_org, g_pos, b_pos, g_neg, b_neg, bn);
    bn_concat_k<<<7500, 256, 0, stream>>>(org0b, p0b, n0b, bn, prelu_w, cb);
    mfma_gemm_mlp_k<<<625, 256, 0, stream>>>(cb, Wb + 49152, out);

    (void)in_sizes; (void)n_in; (void)out_size; (void)ws_size;
}

// Round 5
// 606.350 us; speedup vs baseline: 3.1999x; 3.1999x over previous
//
#include <hip/hip_runtime.h>

#define NNODES 40000
#define NEDGE  640000
#define NBUCK  625          // buckets per sign, 64 rows each
#define ECAP   1408         // per-bucket capacity (mean 1024, sd ~32)

typedef __attribute__((ext_vector_type(8))) short bfrag;
typedef __attribute__((ext_vector_type(4))) float facc;

union bfu { bfrag v; uint u[4]; };

__device__ inline ushort f2bf(float f) {
    uint u = __float_as_uint(f);
    return (ushort)((u + 0x7FFFu + ((u >> 16) & 1u)) >> 16);
}
__device__ inline float bf2f(ushort h) {
    return __uint_as_float(((uint)h) << 16);
}

// ---------------- edge partition into 64-row buckets ----------------

__global__ __launch_bounds__(256) void partition_k(const int* __restrict__ pos_idx,
                                                   const float* __restrict__ pos_w,
                                                   const int* __restrict__ neg_idx,
                                                   const float* __restrict__ neg_w,
                                                   int* __restrict__ ecnt,
                                                   int2* __restrict__ edges) {
    __shared__ int lhist[2 * NBUCK];
    __shared__ int lbase[2 * NBUCK];
    long g0 = (long)blockIdx.x * 16384;
    for (int i = threadIdx.x; i < 2 * NBUCK; i += 256) lhist[i] = 0;
    __syncthreads();
    for (int i = 0; i < 64; ++i) {
        long g = g0 + i * 256 + threadIdx.x;
        if (g < 2 * NEDGE) {
            int sign = g >= NEDGE;
            int e = (int)(g - (long)sign * NEDGE);
            int row = sign ? neg_idx[e] : pos_idx[e];
            atomicAdd(&lhist[sign * NBUCK + (row >> 6)], 1);
        }
    }
    __syncthreads();
    for (int b = threadIdx.x; b < 2 * NBUCK; b += 256) {
        int c = lhist[b];
        lbase[b] = c ? atomicAdd(&ecnt[b], c) : 0;
        lhist[b] = 0;
    }
    __syncthreads();
    for (int i = 0; i < 64; ++i) {
        long g = g0 + i * 256 + threadIdx.x;
        if (g < 2 * NEDGE) {
            int sign = g >= NEDGE;
            int e = (int)(g - (long)sign * NEDGE);
            int row = sign ? neg_idx[e] : pos_idx[e];
            int col = sign ? neg_idx[NEDGE + e] : pos_idx[NEDGE + e];
            float wv = sign ? neg_w[e] : pos_w[e];
            int b = sign * NBUCK + (row >> 6);
            int off = lbase[b] + atomicAdd(&lhist[b], 1);
            if (off < ECAP)
                edges[(long)b * ECAP + off] =
                    make_int2((int)((uint)col | ((uint)(row & 63) << 16)), __float_as_int(wv));
        }
    }
}

// ---------------- bucket-local counting sort -> CSR (in-place) ----------------
// block = one bucket; stage edges in LDS, 64-bin hist+scan, scatter back sorted,
// write rp2[row] = (start, end) absolute positions.

__global__ __launch_bounds__(256) void bucket_csr_k(const int* __restrict__ ecnt,
                                                    int2* __restrict__ edges,
                                                    int2* __restrict__ rp2) {
    __shared__ int2 stage[ECAP];
    __shared__ int hist[64];
    __shared__ int base_[64];
    int b = blockIdx.x;
    int tid = threadIdx.x;
    int cnt = ecnt[b]; if (cnt > ECAP) cnt = ECAP;
    if (tid < 64) hist[tid] = 0;
    __syncthreads();
    long e0 = (long)b * ECAP;
    for (int i = tid; i < cnt; i += 256) {
        int2 e = edges[e0 + i];
        stage[i] = e;
        atomicAdd(&hist[((uint)e.x >> 16) & 63u], 1);
    }
    __syncthreads();
    if (tid < 64) {
        int v = hist[tid];
        int s = v;
#pragma unroll
        for (int off = 1; off < 64; off <<= 1) {
            int t = __shfl_up(s, off);
            if ((tid & 63) >= off) s += t;
        }
        int excl = s - v;
        base_[tid] = excl;
        int sign = b >= NBUCK;
        int r = (b - sign * NBUCK) * 64 + tid;
        rp2[sign * NNODES + r] = make_int2((int)(e0 + excl), (int)(e0 + excl + v));
        hist[tid] = 0;   // reuse as cursor
    }
    __syncthreads();
    for (int i = tid; i < cnt; i += 256) {
        int2 e = stage[i];
        int rl = ((uint)e.x >> 16) & 63u;
        int pos = base_[rl] + atomicAdd(&hist[rl], 1);
        edges[e0 + pos] = make_int2(e.x & 0xFFFF, e.y);
    }
}

// ---------------- pack all W into MFMA B-fragment order ----------------

__global__ __launch_bounds__(256) void pack_all_k(const float* __restrict__ Wo,
                                                  const float* __restrict__ Wp,
                                                  const float* __restrict__ Wn,
                                                  const float* __restrict__ Wm,
                                                  ushort* __restrict__ out) {
    int idx = blockIdx.x * 256 + threadIdx.x;      // 0..98303
    const float* W;
    ushort* dst;
    int local;
    if (idx < 49152) {
        int m = idx >> 14;
        local = idx & 16383;
        W = (m == 0) ? Wo : (m == 1) ? Wp : Wn;
        dst = out + m * 16384;
    } else {
        local = idx - 49152;
        W = Wm;
        dst = out + 49152;
    }
    int j = local & 7, l = (local >> 3) & 63, t = (local >> 9) & 7, ks = local >> 12;
    int k = ks * 32 + (l >> 4) * 8 + j;
    int c = (l & 15) + 16 * t;
    dst[local] = f2bf(W[k * 128 + c]);
}

// ---------------- fused triple MFMA GEMM: x(f32) @ {W_org,W_pos,W_neg} ----------------
// converts x to bf16 fragments in-register; fused per-channel stats for org.

__global__ __launch_bounds__(256) void mfma_gemm3_k(const float* __restrict__ x,
                                                    const ushort* __restrict__ B0,
                                                    const ushort* __restrict__ B1,
                                                    const ushort* __restrict__ B2,
                                                    ushort* __restrict__ O0,
                                                    ushort* __restrict__ O1,
                                                    ushort* __restrict__ O2,
                                                    float* __restrict__ sums,
                                                    float* __restrict__ sumsq) {
    __shared__ float cs[128], cq[128];
    int tid = threadIdx.x;
    int lane = tid & 63, wave = tid >> 6;
    if (tid < 128) { cs[tid] = 0.f; cq[tid] = 0.f; }
    __syncthreads();
    long rbase = (long)blockIdx.x * 64 + wave * 16;
    int r = lane & 15, kg = lane >> 4;
    const float* xr = x + (rbase + r) * 128 + kg * 8;
    bfrag a[4];
#pragma unroll
    for (int ks = 0; ks < 4; ++ks) {
        float4 lo = *(const float4*)(xr + ks * 32);
        float4 hi = *(const float4*)(xr + ks * 32 + 4);
        bfu t;
        t.u[0] = (uint)f2bf(lo.x) | ((uint)f2bf(lo.y) << 16);
        t.u[1] = (uint)f2bf(lo.z) | ((uint)f2bf(lo.w) << 16);
        t.u[2] = (uint)f2bf(hi.x) | ((uint)f2bf(hi.y) << 16);
        t.u[3] = (uint)f2bf(hi.z) | ((uint)f2bf(hi.w) << 16);
        a[ks] = t.v;
    }
    const ushort* Bs[3] = {B0, B1, B2};
    ushort* Os[3] = {O0, O1, O2};
    long orow = rbase + kg * 4;
#pragma unroll
    for (int m = 0; m < 3; ++m) {
        const bfrag* Bq = (const bfrag*)Bs[m] + lane;
        facc acc[8];
#pragma unroll
        for (int t = 0; t < 8; ++t) acc[t] = (facc){0.f, 0.f, 0.f, 0.f};
#pragma unroll
        for (int ks = 0; ks < 4; ++ks)
#pragma unroll
            for (int t = 0; t < 8; ++t)
                acc[t] = __builtin_amdgcn_mfma_f32_16x16x32_bf16(a[ks], Bq[(ks * 8 + t) * 64], acc[t], 0, 0, 0);
        ushort* O = Os[m];
#pragma unroll
        for (int t = 0; t < 8; ++t) {
            float s_ = 0.f, q_ = 0.f;
#pragma unroll
            for (int j = 0; j < 4; ++j) {
                ushort bv = f2bf(acc[t][j]);
                O[(orow + j) * 128 + 16 * t + r] = bv;
                if (m == 0) {
                    float fv = bf2f(bv);
                    s_ += fv;
                    q_ = fmaf(fv, fv, q_);
                }
            }
            if (m == 0) {
                atomicAdd(&cs[16 * t + r], s_);
                atomicAdd(&cq[16 * t + r], q_);
            }
        }
    }
    __syncthreads();
    if (tid < 128) {
        atomicAdd(&sums[tid], cs[tid]);
        atomicAdd(&sumsq[tid], cq[tid]);
    }
}

// ---------------- final MFMA GEMM K=384 with fused BN+PReLU+concat + row-norm ----------------

__global__ __launch_bounds__(256) void mfma_gemm_mlp_k(const ushort* __restrict__ org,
                                                       const ushort* __restrict__ pos,
                                                       const ushort* __restrict__ neg,
                                                       const float* __restrict__ bn,
                                                       const float* __restrict__ prelu_w,
                                                       const ushort* __restrict__ Bp,
                                                       float* __restrict__ Out) {
    int lane = threadIdx.x & 63, wave = threadIdx.x >> 6;
    long rbase = (long)blockIdx.x * 64 + wave * 16;
    int r = lane & 15, kg = lane >> 4;
    float pw = prelu_w[0];
    facc acc[8];
#pragma unroll
    for (int t = 0; t < 8; ++t) acc[t] = (facc){0.f, 0.f, 0.f, 0.f};
    const bfrag* Bq = (const bfrag*)Bp + lane;
#pragma unroll
    for (int ks = 0; ks < 12; ++ks) {
        int c = ks * 32 + kg * 8;          // concat column of first elem
        int s = c >> 7;
        int off = c & 127;
        const ushort* src = (s == 0) ? org : (s == 1) ? pos : neg;
        uint4 u = *(const uint4*)(src + (rbase + r) * 128 + off);
        float4 sc_lo = *(const float4*)(bn + s * 256 + off);
        float4 sc_hi = *(const float4*)(bn + s * 256 + off + 4);
        float4 sh_lo = *(const float4*)(bn + s * 256 + 128 + off);
        float4 sh_hi = *(const float4*)(bn + s * 256 + 128 + off + 4);
        uint uu[4] = {u.x, u.y, u.z, u.w};
        float scv[8] = {sc_lo.x, sc_lo.y, sc_lo.z, sc_lo.w, sc_hi.x, sc_hi.y, sc_hi.z, sc_hi.w};
        float shv[8] = {sh_lo.x, sh_lo.y, sh_lo.z, sh_lo.w, sh_hi.x, sh_hi.y, sh_hi.z, sh_hi.w};
        bfu av;
#pragma unroll
        for (int k = 0; k < 4; ++k) {
            float vx = __uint_as_float(uu[k] << 16);
            float vy = __uint_as_float(uu[k] & 0xFFFF0000u);
            float ox = fmaf(vx, scv[2 * k],     shv[2 * k]);     ox = (ox >= 0.f) ? ox : pw * ox;
            float oy = fmaf(vy, scv[2 * k + 1], shv[2 * k + 1]); oy = (oy >= 0.f) ? oy : pw * oy;
            av.u[k] = (uint)f2bf(ox) | ((uint)f2bf(oy) << 16);
        }
#pragma unroll
        for (int t = 0; t < 8; ++t)
            acc[t] = __builtin_amdgcn_mfma_f32_16x16x32_bf16(av.v, Bq[(ks * 8 + t) * 64], acc[t], 0, 0, 0);
    }
    long orow = rbase + kg * 4;
#pragma unroll
    for (int j = 0; j < 4; ++j) {
        float ss = 0.f;
#pragma unroll
        for (int t = 0; t < 8; ++t) ss = fmaf(acc[t][j], acc[t][j], ss);
        ss += __shfl_xor(ss, 1);
        ss += __shfl_xor(ss, 2);
        ss += __shfl_xor(ss, 4);
        ss += __shfl_xor(ss, 8);
        float inv = 1.f / fmaxf(sqrtf(ss), 1e-12f);
#pragma unroll
        for (int t = 0; t < 8; ++t)
            Out[(orow + j) * 128 + 16 * t + r] = acc[t][j] * inv;
    }
}

// ---------------- SpMM: row-per-wave gather, both signs in one dispatch ----------------
// PHASE 1: out = 2*A@in.  PHASE 2: out = 1.875*A@in - 1.6875*prev + fused stats.

template<int PHASE>
__global__ __launch_bounds__(256) void spmm2_k(const int2* __restrict__ rp2,
                                               const int2* __restrict__ edges,
                                               const uint* __restrict__ p_in,
                                               const uint* __restrict__ n_in,
                                               const uint* __restrict__ p_prev,
                                               const uint* __restrict__ n_prev,
                                               uint* __restrict__ p_out,
                                               uint* __restrict__ n_out,
                                               float* __restrict__ sums,
                                               float* __restrict__ sumsq) {
    __shared__ float st[4][256];
    int bb = blockIdx.x;
    int sign = bb >= 10000;
    int tid = threadIdx.x;
    int r = (bb - sign * 10000) * 4 + (tid >> 6);
    int lane = tid & 63;
    int2 se = rp2[sign * NNODES + r];
    const uint* in = sign ? n_in : p_in;
    float ax = 0.f, ay = 0.f, bx = 0.f, by = 0.f;
    int e = se.x, e1 = se.y;
    for (; e + 4 <= e1; e += 4) {
        int2 c0 = edges[e], c1 = edges[e + 1], c2 = edges[e + 2], c3 = edges[e + 3];
        uint u0 = in[(long)c0.x * 64 + lane];
        uint u1 = in[(long)c1.x * 64 + lane];
        uint u2 = in[(long)c2.x * 64 + lane];
        uint u3 = in[(long)c3.x * 64 + lane];
        float w0 = __int_as_float(c0.y), w1 = __int_as_float(c1.y);
        float w2 = __int_as_float(c2.y), w3 = __int_as_float(c3.y);
        ax = fmaf(w0, __uint_as_float(u0 << 16), ax); ay = fmaf(w0, __uint_as_float(u0 & 0xFFFF0000u), ay);
        bx = fmaf(w1, __uint_as_float(u1 << 16), bx); by = fmaf(w1, __uint_as_float(u1 & 0xFFFF0000u), by);
        ax = fmaf(w2, __uint_as_float(u2 << 16), ax); ay = fmaf(w2, __uint_as_float(u2 & 0xFFFF0000u), ay);
        bx = fmaf(w3, __uint_as_float(u3 << 16), bx); by = fmaf(w3, __uint_as_float(u3 & 0xFFFF0000u), by);
    }
    for (; e < e1; ++e) {
        int2 cw = edges[e];
        float wv = __int_as_float(cw.y);
        uint u = in[(long)cw.x * 64 + lane];
        ax = fmaf(wv, __uint_as_float(u << 16), ax);
        ay = fmaf(wv, __uint_as_float(u & 0xFFFF0000u), ay);
    }
    ax += bx; ay += by;
    if (PHASE == 1) {
        uint* out = sign ? n_out : p_out;
        out[(long)r * 64 + lane] = (uint)f2bf(2.f * ax) | ((uint)f2bf(2.f * ay) << 16);
    } else {
        const uint* prev = sign ? n_prev : p_prev;
        uint* out = sign ? n_out : p_out;
        uint pu = prev[(long)r * 64 + lane];
        float rx = fmaf(1.875f, ax, -1.6875f * __uint_as_float(pu << 16));
        float ry = fmaf(1.875f, ay, -1.6875f * __uint_as_float(pu & 0xFFFF0000u));
        ushort hx = f2bf(rx), hy = f2bf(ry);
        out[(long)r * 64 + lane] = (uint)hx | ((uint)hy << 16);
        float fx = bf2f(hx), fy = bf2f(hy);
        st[0][tid] = fx; st[1][tid] = fx * fx;
        st[2][tid] = fy; st[3][tid] = fy * fy;
        __syncthreads();
        if (tid < 128) {
            int l = tid >> 1;
            int odd = tid & 1;
            int bs = odd ? 2 : 0;
            float S = st[bs][l] + st[bs][64 + l] + st[bs][128 + l] + st[bs][192 + l];
            float Q = st[bs + 1][l] + st[bs + 1][64 + l] + st[bs + 1][128 + l] + st[bs + 1][192 + l];
            int sb = 128 + sign * 128;
            atomicAdd(&sums[sb + tid], S);
            atomicAdd(&sumsq[sb + tid], Q);
        }
    }
}

__global__ void bnfin_k(const float* __restrict__ sum, const float* __restrict__ sumsq,
                        const float* __restrict__ g0, const float* __restrict__ be0,
                        const float* __restrict__ g1, const float* __restrict__ be1,
                        const float* __restrict__ g2, const float* __restrict__ be2,
                        float* __restrict__ bn) {
    int i = threadIdx.x;
    if (i >= 384) return;
    int s = i >> 7, c = i & 127;
    float mean = sum[i] * (1.f / NNODES);
    float var  = sumsq[i] * (1.f / NNODES) - mean * mean;
    const float* g = (s == 0) ? g0 : (s == 1) ? g1 : g2;
    const float* b = (s == 0) ? be0 : (s == 1) ? be1 : be2;
    float sc = g[c] * rsqrtf(var + 1e-5f);
    bn[s * 256 + c]       = sc;
    bn[s * 256 + 128 + c] = b[c] - mean * sc;
}

// ---------------- launch ----------------

extern "C" void kernel_launch(void* const* d_in, const int* in_sizes, int n_in,
                              void* d_out, int out_size, void* d_ws, size_t ws_size,
                              hipStream_t stream) {
    const float* x       = (const float*)d_in[0];
    const int*   pos_idx = (const int*)d_in[1];
    const float* pos_w   = (const float*)d_in[2];
    const int*   neg_idx = (const int*)d_in[3];
    const float* neg_w   = (const float*)d_in[4];
    const float* W_org   = (const float*)d_in[5];
    const float* W_pos   = (const float*)d_in[6];
    const float* W_neg   = (const float*)d_in[7];
    const float* g_org   = (const float*)d_in[8];
    const float* b_org   = (const float*)d_in[9];
    const float* g_pos   = (const float*)d_in[10];
    const float* b_pos   = (const float*)d_in[11];
    const float* g_neg   = (const float*)d_in[12];
    const float* b_neg   = (const float*)d_in[13];
    const float* prelu_w = (const float*)d_in[14];
    const float* W_mlp   = (const float*)d_in[15];
    float* out = (float*)d_out;

    char* ws = (char*)d_ws;
    const size_t FB = (size_t)NNODES * 128 * 2;        // 10,240,000 B
    ushort* org0b = (ushort*)(ws);
    ushort* p0b   = (ushort*)(ws + FB);
    ushort* n0b   = (ushort*)(ws + 2 * FB);
    int2* edges   = (int2*)(ws + 3 * FB);              // 2*NBUCK*ECAP*8 = 14,080,000 B
    char* small   = ws + 3 * FB + 14080000;
    int* ecnt     = (int*)small;                       // 1250*4 = 5000 -> pad 5120
    float* sums   = (float*)(small + 5120);            // 1536
    float* sumsq  = (float*)(small + 5120 + 1536);     // 1536 (memset 0..8192)
    float* bn     = (float*)(small + 8192);            // 3072
    int2* rp2     = (int2*)(small + 8192 + 3072);      // 2*NNODES*8 = 640,000
    ushort* Wb    = (ushort*)(small + 8192 + 3072 + 640000);   // 196,608 B
    uint* t1_pos  = (uint*)d_out;                      // bf16 scratch halves of d_out
    uint* t1_neg  = (uint*)d_out + NNODES * 64;

    hipMemsetAsync(small, 0, 8192, stream);

    partition_k<<<79, 256, 0, stream>>>(pos_idx, pos_w, neg_idx, neg_w, ecnt, edges);
    bucket_csr_k<<<2 * NBUCK, 256, 0, stream>>>(ecnt, edges, rp2);
    pack_all_k<<<384, 256, 0, stream>>>(W_org, W_pos, W_neg, W_mlp, Wb);

    mfma_gemm3_k<<<625, 256, 0, stream>>>(x, Wb, Wb + 16384, Wb + 32768,
                                          org0b, p0b, n0b, sums, sumsq);

    // Jacobi (a=b=1, K=3): x1 = 2*A@x0 ; x2 = 1.875*A@x1 - 1.6875*x0
    spmm2_k<1><<<20000, 256, 0, stream>>>(rp2, edges,
        (const uint*)p0b, (const uint*)n0b, nullptr, nullptr, t1_pos, t1_neg, sums, sumsq);
    spmm2_k<2><<<20000, 256, 0, stream>>>(rp2, edges,
        t1_pos, t1_neg, (const uint*)p0b, (const uint*)n0b, (uint*)p0b, (uint*)n0b, sums, sumsq);

    bnfin_k<<<1, 384, 0, stream>>>(sums, sumsq, g_org, b_org, g_pos, b_pos, g_neg, b_neg, bn);
    mfma_gemm_mlp_k<<<625, 256, 0, stream>>>(org0b, p0b, n0b, bn, prelu_w, Wb + 49152, out);

    (void)in_sizes; (void)n_in; (void)out_size; (void)ws_size;
}

// Round 6
// 386.844 us; speedup vs baseline: 5.0156x; 1.5674x over previous
//
#include <hip/hip_runtime.h>

#define NNODES 40000
#define NEDGE  640000
#define NBUCK  625          // buckets per sign, 64 rows each
#define ECAP   1408         // per-bucket capacity (mean 1024, sd ~32)
#define QSZ16  1280000      // ushorts per quarter table (40000*32)
#define QSZU   640000       // uints per quarter table

typedef __attribute__((ext_vector_type(8))) short bfrag;
typedef __attribute__((ext_vector_type(4))) float facc;

union bfu { bfrag v; uint u[4]; };

__device__ inline ushort f2bf(float f) {
    uint u = __float_as_uint(f);
    return (ushort)((u + 0x7FFFu + ((u >> 16) & 1u)) >> 16);
}
__device__ inline float bf2f(ushort h) {
    return __uint_as_float(((uint)h) << 16);
}
__device__ inline float blo(uint u) { return __uint_as_float(u << 16); }
__device__ inline float bhi(uint u) { return __uint_as_float(u & 0xFFFF0000u); }

// ---------------- edge partition into 64-row buckets ----------------

__global__ __launch_bounds__(256) void partition_k(const int* __restrict__ pos_idx,
                                                   const float* __restrict__ pos_w,
                                                   const int* __restrict__ neg_idx,
                                                   const float* __restrict__ neg_w,
                                                   int* __restrict__ ecnt,
                                                   int2* __restrict__ edges) {
    __shared__ int lhist[2 * NBUCK];
    __shared__ int lbase[2 * NBUCK];
    long g0 = (long)blockIdx.x * 16384;
    for (int i = threadIdx.x; i < 2 * NBUCK; i += 256) lhist[i] = 0;
    __syncthreads();
    for (int i = 0; i < 64; ++i) {
        long g = g0 + i * 256 + threadIdx.x;
        if (g < 2 * NEDGE) {
            int sign = g >= NEDGE;
            int e = (int)(g - (long)sign * NEDGE);
            int row = sign ? neg_idx[e] : pos_idx[e];
            atomicAdd(&lhist[sign * NBUCK + (row >> 6)], 1);
        }
    }
    __syncthreads();
    for (int b = threadIdx.x; b < 2 * NBUCK; b += 256) {
        int c = lhist[b];
        lbase[b] = c ? atomicAdd(&ecnt[b], c) : 0;
        lhist[b] = 0;
    }
    __syncthreads();
    for (int i = 0; i < 64; ++i) {
        long g = g0 + i * 256 + threadIdx.x;
        if (g < 2 * NEDGE) {
            int sign = g >= NEDGE;
            int e = (int)(g - (long)sign * NEDGE);
            int row = sign ? neg_idx[e] : pos_idx[e];
            int col = sign ? neg_idx[NEDGE + e] : pos_idx[NEDGE + e];
            float wv = sign ? neg_w[e] : pos_w[e];
            int b = sign * NBUCK + (row >> 6);
            int off = lbase[b] + atomicAdd(&lhist[b], 1);
            if (off < ECAP)
                edges[(long)b * ECAP + off] =
                    make_int2((int)((uint)col | ((uint)(row & 63) << 16)), __float_as_int(wv));
        }
    }
}

// ---------------- bucket-local counting sort -> CSR (in-place) ----------------

__global__ __launch_bounds__(256) void bucket_csr_k(const int* __restrict__ ecnt,
                                                    int2* __restrict__ edges,
                                                    int2* __restrict__ rp2) {
    __shared__ int2 stage[ECAP];
    __shared__ int hist[64];
    __shared__ int base_[64];
    int b = blockIdx.x;
    int tid = threadIdx.x;
    int cnt = ecnt[b]; if (cnt > ECAP) cnt = ECAP;
    if (tid < 64) hist[tid] = 0;
    __syncthreads();
    long e0 = (long)b * ECAP;
    for (int i = tid; i < cnt; i += 256) {
        int2 e = edges[e0 + i];
        stage[i] = e;
        atomicAdd(&hist[((uint)e.x >> 16) & 63u], 1);
    }
    __syncthreads();
    if (tid < 64) {
        int v = hist[tid];
        int s = v;
#pragma unroll
        for (int off = 1; off < 64; off <<= 1) {
            int t = __shfl_up(s, off);
            if ((tid & 63) >= off) s += t;
        }
        int excl = s - v;
        base_[tid] = excl;
        int sign = b >= NBUCK;
        int r = (b - sign * NBUCK) * 64 + tid;
        rp2[sign * NNODES + r] = make_int2((int)(e0 + excl), (int)(e0 + excl + v));
        hist[tid] = 0;   // reuse as cursor
    }
    __syncthreads();
    for (int i = tid; i < cnt; i += 256) {
        int2 e = stage[i];
        int rl = ((uint)e.x >> 16) & 63u;
        int pos = base_[rl] + atomicAdd(&hist[rl], 1);
        edges[e0 + pos] = make_int2(e.x & 0xFFFF, e.y);
    }
}

// ---------------- pack all W into MFMA B-fragment order ----------------

__global__ __launch_bounds__(256) void pack_all_k(const float* __restrict__ Wo,
                                                  const float* __restrict__ Wp,
                                                  const float* __restrict__ Wn,
                                                  const float* __restrict__ Wm,
                                                  ushort* __restrict__ out) {
    int idx = blockIdx.x * 256 + threadIdx.x;      // 0..98303
    const float* W;
    ushort* dst;
    int local;
    if (idx < 49152) {
        int m = idx >> 14;
        local = idx & 16383;
        W = (m == 0) ? Wo : (m == 1) ? Wp : Wn;
        dst = out + m * 16384;
    } else {
        local = idx - 49152;
        W = Wm;
        dst = out + 49152;
    }
    int j = local & 7, l = (local >> 3) & 63, t = (local >> 9) & 7, ks = local >> 12;
    int k = ks * 32 + (l >> 4) * 8 + j;
    int c = (l & 15) + 16 * t;
    dst[local] = f2bf(W[k * 128 + c]);
}

// ---------------- fused triple MFMA GEMM: x(f32) @ {W_org,W_pos,W_neg} ----------------
// outputs quarter-blocked bf16; fused per-channel stats for org.

__global__ __launch_bounds__(256) void mfma_gemm3_k(const float* __restrict__ x,
                                                    const ushort* __restrict__ B0,
                                                    const ushort* __restrict__ B1,
                                                    const ushort* __restrict__ B2,
                                                    ushort* __restrict__ O0,
                                                    ushort* __restrict__ O1,
                                                    ushort* __restrict__ O2,
                                                    float* __restrict__ sums,
                                                    float* __restrict__ sumsq) {
    __shared__ float cs[128], cq[128];
    int tid = threadIdx.x;
    int lane = tid & 63, wave = tid >> 6;
    if (tid < 128) { cs[tid] = 0.f; cq[tid] = 0.f; }
    __syncthreads();
    long rbase = (long)blockIdx.x * 64 + wave * 16;
    int r = lane & 15, kg = lane >> 4;
    const float* xr = x + (rbase + r) * 128 + kg * 8;
    bfrag a[4];
#pragma unroll
    for (int ks = 0; ks < 4; ++ks) {
        float4 lo = *(const float4*)(xr + ks * 32);
        float4 hi = *(const float4*)(xr + ks * 32 + 4);
        bfu t;
        t.u[0] = (uint)f2bf(lo.x) | ((uint)f2bf(lo.y) << 16);
        t.u[1] = (uint)f2bf(lo.z) | ((uint)f2bf(lo.w) << 16);
        t.u[2] = (uint)f2bf(hi.x) | ((uint)f2bf(hi.y) << 16);
        t.u[3] = (uint)f2bf(hi.z) | ((uint)f2bf(hi.w) << 16);
        a[ks] = t.v;
    }
    const ushort* Bs[3] = {B0, B1, B2};
    ushort* Os[3] = {O0, O1, O2};
    long orow = rbase + kg * 4;
#pragma unroll
    for (int m = 0; m < 3; ++m) {
        const bfrag* Bq = (const bfrag*)Bs[m] + lane;
        facc acc[8];
#pragma unroll
        for (int t = 0; t < 8; ++t) acc[t] = (facc){0.f, 0.f, 0.f, 0.f};
#pragma unroll
        for (int ks = 0; ks < 4; ++ks)
#pragma unroll
            for (int t = 0; t < 8; ++t)
                acc[t] = __builtin_amdgcn_mfma_f32_16x16x32_bf16(a[ks], Bq[(ks * 8 + t) * 64], acc[t], 0, 0, 0);
        ushort* O = Os[m];
#pragma unroll
        for (int t = 0; t < 8; ++t) {
            float s_ = 0.f, q_ = 0.f;
            // channel c = 16t + r -> blocked: q = t>>1, cc = (t&1)*16 + r
            long qb = (long)(t >> 1) * QSZ16 + (t & 1) * 16 + r;
#pragma unroll
            for (int j = 0; j < 4; ++j) {
                ushort bv = f2bf(acc[t][j]);
                O[qb + (orow + j) * 32] = bv;
                if (m == 0) {
                    float fv = bf2f(bv);
                    s_ += fv;
                    q_ = fmaf(fv, fv, q_);
                }
            }
            if (m == 0) {
                atomicAdd(&cs[16 * t + r], s_);
                atomicAdd(&cq[16 * t + r], q_);
            }
        }
    }
    __syncthreads();
    if (tid < 128) {
        atomicAdd(&sums[tid], cs[tid]);
        atomicAdd(&sumsq[tid], cq[tid]);
    }
}

// ---------------- quarter-blocked SpMM ----------------
// grid = 40000 blocks: sign-major (20000 each), then quarter (5000 each), then row-group.
// block = 4 waves x 2 rows; wave: 16-lane group g handles edge e+g, lane u = 2 channels.
// PHASE 1: out = 2*A@in.  PHASE 2: out = 1.875*A@in - 1.6875*prev.

template<int PHASE>
__global__ __launch_bounds__(256) void spmmq_k(const int2* __restrict__ rp2,
                                               const int2* __restrict__ edges,
                                               const uint* __restrict__ p_in,
                                               const uint* __restrict__ n_in,
                                               const uint* __restrict__ p_prev,
                                               const uint* __restrict__ n_prev,
                                               uint* __restrict__ p_out,
                                               uint* __restrict__ n_out) {
    int bb = blockIdx.x;
    int sign = bb >= 20000;
    int rem = bb - sign * 20000;
    int q = rem / 5000;
    int rg = rem - q * 5000;
    int tid = threadIdx.x;
    int w = tid >> 6, lane = tid & 63;
    int u = lane & 15, g = lane >> 4;
    const uint* in = (sign ? n_in : p_in) + q * QSZU;
    uint* out = (sign ? n_out : p_out) + q * QSZU;
    const uint* prev = (PHASE == 2) ? ((sign ? n_prev : p_prev) + q * QSZU) : nullptr;
    const int2* rp = rp2 + sign * NNODES;
#pragma unroll
    for (int rr = 0; rr < 2; ++rr) {
        int r = rg * 8 + w * 2 + rr;
        int2 se = rp[r];
        float ax = 0.f, ay = 0.f, bx = 0.f, by = 0.f;
        int e = se.x, e1 = se.y;
        for (; e + 8 <= e1; e += 8) {
            int2 eda = edges[e + g];
            int2 edb = edges[e + 4 + g];
            uint ga = in[(uint)eda.x * 16 + u];
            uint gb = in[(uint)edb.x * 16 + u];
            float wa = __int_as_float(eda.y), wb = __int_as_float(edb.y);
            ax = fmaf(wa, blo(ga), ax); ay = fmaf(wa, bhi(ga), ay);
            bx = fmaf(wb, blo(gb), bx); by = fmaf(wb, bhi(gb), by);
        }
        for (; e < e1; e += 4) {
            int kk = e + g;
            int2 ed = (kk < e1) ? edges[kk] : make_int2(0, 0);
            uint gv = in[(uint)ed.x * 16 + u];
            float wv = __int_as_float(ed.y);
            ax = fmaf(wv, blo(gv), ax); ay = fmaf(wv, bhi(gv), ay);
        }
        ax += bx; ay += by;
        ax += __shfl_xor(ax, 16); ay += __shfl_xor(ay, 16);
        ax += __shfl_xor(ax, 32); ay += __shfl_xor(ay, 32);
        if (g == 0) {
            if (PHASE == 1) {
                out[r * 16 + u] = (uint)f2bf(2.f * ax) | ((uint)f2bf(2.f * ay) << 16);
            } else {
                uint pu = prev[r * 16 + u];
                float rx = fmaf(1.875f, ax, -1.6875f * blo(pu));
                float ry = fmaf(1.875f, ay, -1.6875f * bhi(pu));
                out[r * 16 + u] = (uint)f2bf(rx) | ((uint)f2bf(ry) << 16);
            }
        }
    }
}

// ---------------- batch stats for pos & neg (quarter-blocked bf16 input) ----------------

__global__ __launch_bounds__(256) void stats2_k(const ushort* __restrict__ pos,
                                                const ushort* __restrict__ neg,
                                                float* __restrict__ sums,
                                                float* __restrict__ sumsq) {
    int b = blockIdx.x;            // 626 blocks
    int sign = b >= 313;
    int blk = b - sign * 313;
    const ushort* buf = sign ? neg : pos;
    int c = threadIdx.x & 127, half = threadIdx.x >> 7;
    int qq = c >> 5, cc = c & 31;
    const ushort* base = buf + (long)qq * QSZ16 + cc;
    int r0 = blk * 128;
    int rend = r0 + 128; if (rend > NNODES) rend = NNODES;
    float s = 0.f, s2 = 0.f;
    for (int r = r0 + half; r < rend; r += 2) {
        float v = bf2f(base[r * 32]);
        s += v;
        s2 = fmaf(v, v, s2);
    }
    __shared__ float sh[256], sh2[256];
    sh[threadIdx.x] = s; sh2[threadIdx.x] = s2;
    __syncthreads();
    if (threadIdx.x < 128) {
        int sb = 128 + sign * 128;
        atomicAdd(&sums[sb + c],  sh[c]  + sh[c + 128]);
        atomicAdd(&sumsq[sb + c], sh2[c] + sh2[c + 128]);
    }
}

__global__ void bnfin_k(const float* __restrict__ sum, const float* __restrict__ sumsq,
                        const float* __restrict__ g0, const float* __restrict__ be0,
                        const float* __restrict__ g1, const float* __restrict__ be1,
                        const float* __restrict__ g2, const float* __restrict__ be2,
                        float* __restrict__ bn) {
    int i = threadIdx.x;
    if (i >= 384) return;
    int s = i >> 7, c = i & 127;
    float mean = sum[i] * (1.f / NNODES);
    float var  = sumsq[i] * (1.f / NNODES) - mean * mean;
    const float* g = (s == 0) ? g0 : (s == 1) ? g1 : g2;
    const float* b = (s == 0) ? be0 : (s == 1) ? be1 : be2;
    float sc = g[c] * rsqrtf(var + 1e-5f);
    bn[s * 256 + c]       = sc;
    bn[s * 256 + 128 + c] = b[c] - mean * sc;
}

// ---------------- final MFMA GEMM K=384 with fused BN+PReLU+concat + row-norm ----------------

__global__ __launch_bounds__(256) void mfma_gemm_mlp_k(const ushort* __restrict__ org,
                                                       const ushort* __restrict__ pos,
                                                       const ushort* __restrict__ neg,
                                                       const float* __restrict__ bn,
                                                       const float* __restrict__ prelu_w,
                                                       const ushort* __restrict__ Bp,
                                                       float* __restrict__ Out) {
    int lane = threadIdx.x & 63, wave = threadIdx.x >> 6;
    long rbase = (long)blockIdx.x * 64 + wave * 16;
    int r = lane & 15, kg = lane >> 4;
    float pw = prelu_w[0];
    facc acc[8];
#pragma unroll
    for (int t = 0; t < 8; ++t) acc[t] = (facc){0.f, 0.f, 0.f, 0.f};
    const bfrag* Bq = (const bfrag*)Bp + lane;
#pragma unroll
    for (int ks = 0; ks < 12; ++ks) {
        int c = ks * 32 + kg * 8;          // concat column of first elem
        int s = c >> 7;
        int off = c & 127;
        const ushort* src = (s == 0) ? org : (s == 1) ? pos : neg;
        const uint* srcu = (const uint*)src;
        uint4 u = *(const uint4*)(srcu + (long)(off >> 5) * QSZU + (rbase + r) * 16 + ((off & 31) >> 1));
        float4 sc_lo = *(const float4*)(bn + s * 256 + off);
        float4 sc_hi = *(const float4*)(bn + s * 256 + off + 4);
        float4 sh_lo = *(const float4*)(bn + s * 256 + 128 + off);
        float4 sh_hi = *(const float4*)(bn + s * 256 + 128 + off + 4);
        uint uu[4] = {u.x, u.y, u.z, u.w};
        float scv[8] = {sc_lo.x, sc_lo.y, sc_lo.z, sc_lo.w, sc_hi.x, sc_hi.y, sc_hi.z, sc_hi.w};
        float shv[8] = {sh_lo.x, sh_lo.y, sh_lo.z, sh_lo.w, sh_hi.x, sh_hi.y, sh_hi.z, sh_hi.w};
        bfu av;
#pragma unroll
        for (int k = 0; k < 4; ++k) {
            float vx = __uint_as_float(uu[k] << 16);
            float vy = __uint_as_float(uu[k] & 0xFFFF0000u);
            float ox = fmaf(vx, scv[2 * k],     shv[2 * k]);     ox = (ox >= 0.f) ? ox : pw * ox;
            float oy = fmaf(vy, scv[2 * k + 1], shv[2 * k + 1]); oy = (oy >= 0.f) ? oy : pw * oy;
            av.u[k] = (uint)f2bf(ox) | ((uint)f2bf(oy) << 16);
        }
#pragma unroll
        for (int t = 0; t < 8; ++t)
            acc[t] = __builtin_amdgcn_mfma_f32_16x16x32_bf16(av.v, Bq[(ks * 8 + t) * 64], acc[t], 0, 0, 0);
    }
    long orow = rbase + kg * 4;
#pragma unroll
    for (int j = 0; j < 4; ++j) {
        float ss = 0.f;
#pragma unroll
        for (int t = 0; t < 8; ++t) ss = fmaf(acc[t][j], acc[t][j], ss);
        ss += __shfl_xor(ss, 1);
        ss += __shfl_xor(ss, 2);
        ss += __shfl_xor(ss, 4);
        ss += __shfl_xor(ss, 8);
        float inv = 1.f / fmaxf(sqrtf(ss), 1e-12f);
#pragma unroll
        for (int t = 0; t < 8; ++t)
            Out[(orow + j) * 128 + 16 * t + r] = acc[t][j] * inv;
    }
}

// ---------------- launch ----------------

extern "C" void kernel_launch(void* const* d_in, const int* in_sizes, int n_in,
                              void* d_out, int out_size, void* d_ws, size_t ws_size,
                              hipStream_t stream) {
    const float* x       = (const float*)d_in[0];
    const int*   pos_idx = (const int*)d_in[1];
    const float* pos_w   = (const float*)d_in[2];
    const int*   neg_idx = (const int*)d_in[3];
    const float* neg_w   = (const float*)d_in[4];
    const float* W_org   = (const float*)d_in[5];
    const float* W_pos   = (const float*)d_in[6];
    const float* W_neg   = (const float*)d_in[7];
    const float* g_org   = (const float*)d_in[8];
    const float* b_org   = (const float*)d_in[9];
    const float* g_pos   = (const float*)d_in[10];
    const float* b_pos   = (const float*)d_in[11];
    const float* g_neg   = (const float*)d_in[12];
    const float* b_neg   = (const float*)d_in[13];
    const float* prelu_w = (const float*)d_in[14];
    const float* W_mlp   = (const float*)d_in[15];
    float* out = (float*)d_out;

    char* ws = (char*)d_ws;
    const size_t FB = (size_t)NNODES * 128 * 2;        // 10,240,000 B per feature buffer
    ushort* org0b = (ushort*)(ws);
    ushort* p0b   = (ushort*)(ws + FB);
    ushort* n0b   = (ushort*)(ws + 2 * FB);
    int2* edges   = (int2*)(ws + 3 * FB);              // 14,080,000 B
    char* small   = ws + 3 * FB + 14080000;
    int* ecnt     = (int*)small;                       // 5000 -> pad 5120
    float* sums   = (float*)(small + 5120);            // 1536
    float* sumsq  = (float*)(small + 5120 + 1536);     // 1536 (memset 0..8192)
    float* bn     = (float*)(small + 8192);            // 3072
    int2* rp2     = (int2*)(small + 8192 + 3072);      // 640,000
    ushort* Wb    = (ushort*)(small + 8192 + 3072 + 640000);   // 196,608 B
    uint* t1_pos  = (uint*)d_out;                      // blocked bf16 scratch halves of d_out
    uint* t1_neg  = (uint*)d_out + 4 * QSZU;

    hipMemsetAsync(small, 0, 8192, stream);

    partition_k<<<79, 256, 0, stream>>>(pos_idx, pos_w, neg_idx, neg_w, ecnt, edges);
    bucket_csr_k<<<2 * NBUCK, 256, 0, stream>>>(ecnt, edges, rp2);
    pack_all_k<<<384, 256, 0, stream>>>(W_org, W_pos, W_neg, W_mlp, Wb);

    mfma_gemm3_k<<<625, 256, 0, stream>>>(x, Wb, Wb + 16384, Wb + 32768,
                                          org0b, p0b, n0b, sums, sumsq);

    // Jacobi (a=b=1, K=3): x1 = 2*A@x0 ; x2 = 1.875*A@x1 - 1.6875*x0
    spmmq_k<1><<<40000, 256, 0, stream>>>(rp2, edges,
        (const uint*)p0b, (const uint*)n0b, nullptr, nullptr, t1_pos, t1_neg);
    spmmq_k<2><<<40000, 256, 0, stream>>>(rp2, edges,
        t1_pos, t1_neg, (const uint*)p0b, (const uint*)n0b, (uint*)p0b, (uint*)n0b);

    stats2_k<<<626, 256, 0, stream>>>(p0b, n0b, sums, sumsq);
    bnfin_k<<<1, 384, 0, stream>>>(sums, sumsq, g_org, b_org, g_pos, b_pos, g_neg, b_neg, bn);
    mfma_gemm_mlp_k<<<625, 256, 0, stream>>>(org0b, p0b, n0b, bn, prelu_w, Wb + 49152, out);

    (void)in_sizes; (void)n_in; (void)out_size; (void)ws_size;
}

// Round 7
// 336.870 us; speedup vs baseline: 5.7596x; 1.1483x over previous
//
#include <hip/hip_runtime.h>

#define NNODES 40000
#define NEDGE  640000
#define NBUCK  625          // buckets per sign, 64 rows each
#define ECAP   1408         // per-bucket capacity (mean 1024, sd ~32)
#define QSZ16  1280000      // ushorts per quarter table (40000*32)
#define QSZU   640000       // uints per quarter table

typedef __attribute__((ext_vector_type(8))) short bfrag;
typedef __attribute__((ext_vector_type(4))) float facc;

union bfu { bfrag v; uint u[4]; };

__device__ inline ushort f2bf(float f) {
    uint u = __float_as_uint(f);
    return (ushort)((u + 0x7FFFu + ((u >> 16) & 1u)) >> 16);
}
__device__ inline float bf2f(ushort h) {
    return __uint_as_float(((uint)h) << 16);
}
__device__ inline float blo(uint u) { return __uint_as_float(u << 16); }
__device__ inline float bhi(uint u) { return __uint_as_float(u & 0xFFFF0000u); }

// ---------------- edge partition into 64-row buckets ----------------

__global__ __launch_bounds__(256) void partition_k(const int* __restrict__ pos_idx,
                                                   const float* __restrict__ pos_w,
                                                   const int* __restrict__ neg_idx,
                                                   const float* __restrict__ neg_w,
                                                   int* __restrict__ ecnt,
                                                   int2* __restrict__ edges) {
    __shared__ int lhist[2 * NBUCK];
    __shared__ int lbase[2 * NBUCK];
    long g0 = (long)blockIdx.x * 16384;
    for (int i = threadIdx.x; i < 2 * NBUCK; i += 256) lhist[i] = 0;
    __syncthreads();
    for (int i = 0; i < 64; ++i) {
        long g = g0 + i * 256 + threadIdx.x;
        if (g < 2 * NEDGE) {
            int sign = g >= NEDGE;
            int e = (int)(g - (long)sign * NEDGE);
            int row = sign ? neg_idx[e] : pos_idx[e];
            atomicAdd(&lhist[sign * NBUCK + (row >> 6)], 1);
        }
    }
    __syncthreads();
    for (int b = threadIdx.x; b < 2 * NBUCK; b += 256) {
        int c = lhist[b];
        lbase[b] = c ? atomicAdd(&ecnt[b], c) : 0;
        lhist[b] = 0;
    }
    __syncthreads();
    for (int i = 0; i < 64; ++i) {
        long g = g0 + i * 256 + threadIdx.x;
        if (g < 2 * NEDGE) {
            int sign = g >= NEDGE;
            int e = (int)(g - (long)sign * NEDGE);
            int row = sign ? neg_idx[e] : pos_idx[e];
            int col = sign ? neg_idx[NEDGE + e] : pos_idx[NEDGE + e];
            float wv = sign ? neg_w[e] : pos_w[e];
            int b = sign * NBUCK + (row >> 6);
            int off = lbase[b] + atomicAdd(&lhist[b], 1);
            if (off < ECAP)
                edges[(long)b * ECAP + off] =
                    make_int2((int)((uint)col | ((uint)(row & 63) << 16)), __float_as_int(wv));
        }
    }
}

// ---------------- bucket-local counting sort -> CSR (in-place) ----------------

__global__ __launch_bounds__(256) void bucket_csr_k(const int* __restrict__ ecnt,
                                                    int2* __restrict__ edges,
                                                    int2* __restrict__ rp2) {
    __shared__ int2 stage[ECAP];
    __shared__ int hist[64];
    __shared__ int base_[64];
    int b = blockIdx.x;
    int tid = threadIdx.x;
    int cnt = ecnt[b]; if (cnt > ECAP) cnt = ECAP;
    if (tid < 64) hist[tid] = 0;
    __syncthreads();
    long e0 = (long)b * ECAP;
    for (int i = tid; i < cnt; i += 256) {
        int2 e = edges[e0 + i];
        stage[i] = e;
        atomicAdd(&hist[((uint)e.x >> 16) & 63u], 1);
    }
    __syncthreads();
    if (tid < 64) {
        int v = hist[tid];
        int s = v;
#pragma unroll
        for (int off = 1; off < 64; off <<= 1) {
            int t = __shfl_up(s, off);
            if ((tid & 63) >= off) s += t;
        }
        int excl = s - v;
        base_[tid] = excl;
        int sign = b >= NBUCK;
        int r = (b - sign * NBUCK) * 64 + tid;
        rp2[sign * NNODES + r] = make_int2((int)(e0 + excl), (int)(e0 + excl + v));
        hist[tid] = 0;   // reuse as cursor
    }
    __syncthreads();
    for (int i = tid; i < cnt; i += 256) {
        int2 e = stage[i];
        int rl = ((uint)e.x >> 16) & 63u;
        int pos = base_[rl] + atomicAdd(&hist[rl], 1);
        edges[e0 + pos] = make_int2(e.x & 0xFFFF, e.y);
    }
}

// ---------------- pack all W into MFMA B-fragment order ----------------

__global__ __launch_bounds__(256) void pack_all_k(const float* __restrict__ Wo,
                                                  const float* __restrict__ Wp,
                                                  const float* __restrict__ Wn,
                                                  const float* __restrict__ Wm,
                                                  ushort* __restrict__ out) {
    int idx = blockIdx.x * 256 + threadIdx.x;      // 0..98303
    const float* W;
    ushort* dst;
    int local;
    if (idx < 49152) {
        int m = idx >> 14;
        local = idx & 16383;
        W = (m == 0) ? Wo : (m == 1) ? Wp : Wn;
        dst = out + m * 16384;
    } else {
        local = idx - 49152;
        W = Wm;
        dst = out + 49152;
    }
    int j = local & 7, l = (local >> 3) & 63, t = (local >> 9) & 7, ks = local >> 12;
    int k = ks * 32 + (l >> 4) * 8 + j;
    int c = (l & 15) + 16 * t;
    dst[local] = f2bf(W[k * 128 + c]);
}

// ---------------- fused triple MFMA GEMM: x(f32) @ {W_org,W_pos,W_neg} ----------------
// outputs quarter-blocked bf16; fused per-channel stats for org.

__global__ __launch_bounds__(256) void mfma_gemm3_k(const float* __restrict__ x,
                                                    const ushort* __restrict__ B0,
                                                    const ushort* __restrict__ B1,
                                                    const ushort* __restrict__ B2,
                                                    ushort* __restrict__ O0,
                                                    ushort* __restrict__ O1,
                                                    ushort* __restrict__ O2,
                                                    float* __restrict__ sums,
                                                    float* __restrict__ sumsq) {
    __shared__ float cs[128], cq[128];
    int tid = threadIdx.x;
    int lane = tid & 63, wave = tid >> 6;
    if (tid < 128) { cs[tid] = 0.f; cq[tid] = 0.f; }
    __syncthreads();
    long rbase = (long)blockIdx.x * 64 + wave * 16;
    int r = lane & 15, kg = lane >> 4;
    const float* xr = x + (rbase + r) * 128 + kg * 8;
    bfrag a[4];
#pragma unroll
    for (int ks = 0; ks < 4; ++ks) {
        float4 lo = *(const float4*)(xr + ks * 32);
        float4 hi = *(const float4*)(xr + ks * 32 + 4);
        bfu t;
        t.u[0] = (uint)f2bf(lo.x) | ((uint)f2bf(lo.y) << 16);
        t.u[1] = (uint)f2bf(lo.z) | ((uint)f2bf(lo.w) << 16);
        t.u[2] = (uint)f2bf(hi.x) | ((uint)f2bf(hi.y) << 16);
        t.u[3] = (uint)f2bf(hi.z) | ((uint)f2bf(hi.w) << 16);
        a[ks] = t.v;
    }
    const ushort* Bs[3] = {B0, B1, B2};
    ushort* Os[3] = {O0, O1, O2};
    long orow = rbase + kg * 4;
#pragma unroll
    for (int m = 0; m < 3; ++m) {
        const bfrag* Bq = (const bfrag*)Bs[m] + lane;
        facc acc[8];
#pragma unroll
        for (int t = 0; t < 8; ++t) acc[t] = (facc){0.f, 0.f, 0.f, 0.f};
#pragma unroll
        for (int ks = 0; ks < 4; ++ks)
#pragma unroll
            for (int t = 0; t < 8; ++t)
                acc[t] = __builtin_amdgcn_mfma_f32_16x16x32_bf16(a[ks], Bq[(ks * 8 + t) * 64], acc[t], 0, 0, 0);
        ushort* O = Os[m];
#pragma unroll
        for (int t = 0; t < 8; ++t) {
            float s_ = 0.f, q_ = 0.f;
            // channel c = 16t + r -> blocked: q = t>>1, cc = (t&1)*16 + r
            long qb = (long)(t >> 1) * QSZ16 + (t & 1) * 16 + r;
#pragma unroll
            for (int j = 0; j < 4; ++j) {
                ushort bv = f2bf(acc[t][j]);
                O[qb + (orow + j) * 32] = bv;
                if (m == 0) {
                    float fv = bf2f(bv);
                    s_ += fv;
                    q_ = fmaf(fv, fv, q_);
                }
            }
            if (m == 0) {
                atomicAdd(&cs[16 * t + r], s_);
                atomicAdd(&cq[16 * t + r], q_);
            }
        }
    }
    __syncthreads();
    if (tid < 128) {
        atomicAdd(&sums[tid], cs[tid]);
        atomicAdd(&sumsq[tid], cq[tid]);
    }
}

// ---------------- quarter-blocked SpMM, XCD-pinned groups ----------------
// 40000 blocks; grp = blockIdx.x & 7 (hardware round-robins blocks across the
// 8 XCDs by blockIdx % 8, so each (sign,quarter) group's 2.56 MB table stays
// resident in ONE XCD's L2). rg = blockIdx.x >> 3 (0..4999).
// block = 4 waves x 2 rows; wave: 8-lane group g handles edge e+g (uint2 = 4ch).

template<int PHASE>
__global__ __launch_bounds__(256) void spmmq_k(const int2* __restrict__ rp2,
                                               const int2* __restrict__ edges,
                                               const uint* __restrict__ p_in,
                                               const uint* __restrict__ n_in,
                                               const uint* __restrict__ p_prev,
                                               const uint* __restrict__ n_prev,
                                               uint* __restrict__ p_out,
                                               uint* __restrict__ n_out) {
    int grp = blockIdx.x & 7;
    int rg  = blockIdx.x >> 3;
    int sign = grp >> 2, q = grp & 3;
    int tid = threadIdx.x;
    int w = tid >> 6, lane = tid & 63;
    int u = lane & 7, g = lane >> 3;
    const uint2* in = (const uint2*)((sign ? n_in : p_in) + q * QSZU);
    uint2* out = (uint2*)((sign ? n_out : p_out) + q * QSZU);
    const uint2* prev = (PHASE == 2) ? (const uint2*)((sign ? n_prev : p_prev) + q * QSZU) : nullptr;
    const int2* rp = rp2 + sign * NNODES;
#pragma unroll
    for (int rr = 0; rr < 2; ++rr) {
        int r = rg * 8 + w * 2 + rr;
        int2 se = rp[r];
        float ax = 0.f, ay = 0.f, az = 0.f, aw = 0.f;
        float bx = 0.f, by = 0.f, bz = 0.f, bw = 0.f;
        int e = se.x, e1 = se.y;
        for (; e + 16 <= e1; e += 16) {
            int2 eda = edges[e + g];
            int2 edb = edges[e + 8 + g];
            uint2 ga = in[(uint)eda.x * 8 + u];
            uint2 gb = in[(uint)edb.x * 8 + u];
            float wa = __int_as_float(eda.y), wb = __int_as_float(edb.y);
            ax = fmaf(wa, blo(ga.x), ax); ay = fmaf(wa, bhi(ga.x), ay);
            az = fmaf(wa, blo(ga.y), az); aw = fmaf(wa, bhi(ga.y), aw);
            bx = fmaf(wb, blo(gb.x), bx); by = fmaf(wb, bhi(gb.x), by);
            bz = fmaf(wb, blo(gb.y), bz); bw = fmaf(wb, bhi(gb.y), bw);
        }
        for (; e < e1; e += 8) {
            int kk = e + g;
            int2 ed = (kk < e1) ? edges[kk] : make_int2(0, 0);
            uint2 gv = in[(uint)ed.x * 8 + u];
            float wv = __int_as_float(ed.y);
            ax = fmaf(wv, blo(gv.x), ax); ay = fmaf(wv, bhi(gv.x), ay);
            az = fmaf(wv, blo(gv.y), az); aw = fmaf(wv, bhi(gv.y), aw);
        }
        ax += bx; ay += by; az += bz; aw += bw;
        ax += __shfl_xor(ax, 8);  ay += __shfl_xor(ay, 8);
        az += __shfl_xor(az, 8);  aw += __shfl_xor(aw, 8);
        ax += __shfl_xor(ax, 16); ay += __shfl_xor(ay, 16);
        az += __shfl_xor(az, 16); aw += __shfl_xor(aw, 16);
        ax += __shfl_xor(ax, 32); ay += __shfl_xor(ay, 32);
        az += __shfl_xor(az, 32); aw += __shfl_xor(aw, 32);
        if (g == 0) {
            uint2 res;
            if (PHASE == 1) {
                res.x = (uint)f2bf(2.f * ax) | ((uint)f2bf(2.f * ay) << 16);
                res.y = (uint)f2bf(2.f * az) | ((uint)f2bf(2.f * aw) << 16);
            } else {
                uint2 pu = prev[r * 8 + u];
                float rx = fmaf(1.875f, ax, -1.6875f * blo(pu.x));
                float ry = fmaf(1.875f, ay, -1.6875f * bhi(pu.x));
                float rz = fmaf(1.875f, az, -1.6875f * blo(pu.y));
                float rw = fmaf(1.875f, aw, -1.6875f * bhi(pu.y));
                res.x = (uint)f2bf(rx) | ((uint)f2bf(ry) << 16);
                res.y = (uint)f2bf(rz) | ((uint)f2bf(rw) << 16);
            }
            out[r * 8 + u] = res;
        }
    }
}

// ---------------- batch stats for pos & neg (quarter-blocked bf16 input) ----------------

__global__ __launch_bounds__(256) void stats2_k(const ushort* __restrict__ pos,
                                                const ushort* __restrict__ neg,
                                                float* __restrict__ sums,
                                                float* __restrict__ sumsq) {
    int b = blockIdx.x;            // 626 blocks
    int sign = b >= 313;
    int blk = b - sign * 313;
    const ushort* buf = sign ? neg : pos;
    int c = threadIdx.x & 127, half = threadIdx.x >> 7;
    int qq = c >> 5, cc = c & 31;
    const ushort* base = buf + (long)qq * QSZ16 + cc;
    int r0 = blk * 128;
    int rend = r0 + 128; if (rend > NNODES) rend = NNODES;
    float s = 0.f, s2 = 0.f;
    for (int r = r0 + half; r < rend; r += 2) {
        float v = bf2f(base[r * 32]);
        s += v;
        s2 = fmaf(v, v, s2);
    }
    __shared__ float sh[256], sh2[256];
    sh[threadIdx.x] = s; sh2[threadIdx.x] = s2;
    __syncthreads();
    if (threadIdx.x < 128) {
        int sb = 128 + sign * 128;
        atomicAdd(&sums[sb + c],  sh[c]  + sh[c + 128]);
        atomicAdd(&sumsq[sb + c], sh2[c] + sh2[c + 128]);
    }
}

__global__ void bnfin_k(const float* __restrict__ sum, const float* __restrict__ sumsq,
                        const float* __restrict__ g0, const float* __restrict__ be0,
                        const float* __restrict__ g1, const float* __restrict__ be1,
                        const float* __restrict__ g2, const float* __restrict__ be2,
                        float* __restrict__ bn) {
    int i = threadIdx.x;
    if (i >= 384) return;
    int s = i >> 7, c = i & 127;
    float mean = sum[i] * (1.f / NNODES);
    float var  = sumsq[i] * (1.f / NNODES) - mean * mean;
    const float* g = (s == 0) ? g0 : (s == 1) ? g1 : g2;
    const float* b = (s == 0) ? be0 : (s == 1) ? be1 : be2;
    float sc = g[c] * rsqrtf(var + 1e-5f);
    bn[s * 256 + c]       = sc;
    bn[s * 256 + 128 + c] = b[c] - mean * sc;
}

// ---------------- final MFMA GEMM K=384 with fused BN+PReLU+concat + row-norm ----------------

__global__ __launch_bounds__(256) void mfma_gemm_mlp_k(const ushort* __restrict__ org,
                                                       const ushort* __restrict__ pos,
                                                       const ushort* __restrict__ neg,
                                                       const float* __restrict__ bn,
                                                       const float* __restrict__ prelu_w,
                                                       const ushort* __restrict__ Bp,
                                                       float* __restrict__ Out) {
    int lane = threadIdx.x & 63, wave = threadIdx.x >> 6;
    long rbase = (long)blockIdx.x * 64 + wave * 16;
    int r = lane & 15, kg = lane >> 4;
    float pw = prelu_w[0];
    facc acc[8];
#pragma unroll
    for (int t = 0; t < 8; ++t) acc[t] = (facc){0.f, 0.f, 0.f, 0.f};
    const bfrag* Bq = (const bfrag*)Bp + lane;
#pragma unroll
    for (int ks = 0; ks < 12; ++ks) {
        int c = ks * 32 + kg * 8;          // concat column of first elem
        int s = c >> 7;
        int off = c & 127;
        const ushort* src = (s == 0) ? org : (s == 1) ? pos : neg;
        const uint* srcu = (const uint*)src;
        uint4 u = *(const uint4*)(srcu + (long)(off >> 5) * QSZU + (rbase + r) * 16 + ((off & 31) >> 1));
        float4 sc_lo = *(const float4*)(bn + s * 256 + off);
        float4 sc_hi = *(const float4*)(bn + s * 256 + off + 4);
        float4 sh_lo = *(const float4*)(bn + s * 256 + 128 + off);
        float4 sh_hi = *(const float4*)(bn + s * 256 + 128 + off + 4);
        uint uu[4] = {u.x, u.y, u.z, u.w};
        float scv[8] = {sc_lo.x, sc_lo.y, sc_lo.z, sc_lo.w, sc_hi.x, sc_hi.y, sc_hi.z, sc_hi.w};
        float shv[8] = {sh_lo.x, sh_lo.y, sh_lo.z, sh_lo.w, sh_hi.x, sh_hi.y, sh_hi.z, sh_hi.w};
        bfu av;
#pragma unroll
        for (int k = 0; k < 4; ++k) {
            float vx = __uint_as_float(uu[k] << 16);
            float vy = __uint_as_float(uu[k] & 0xFFFF0000u);
            float ox = fmaf(vx, scv[2 * k],     shv[2 * k]);     ox = (ox >= 0.f) ? ox : pw * ox;
            float oy = fmaf(vy, scv[2 * k + 1], shv[2 * k + 1]); oy = (oy >= 0.f) ? oy : pw * oy;
            av.u[k] = (uint)f2bf(ox) | ((uint)f2bf(oy) << 16);
        }
#pragma unroll
        for (int t = 0; t < 8; ++t)
            acc[t] = __builtin_amdgcn_mfma_f32_16x16x32_bf16(av.v, Bq[(ks * 8 + t) * 64], acc[t], 0, 0, 0);
    }
    long orow = rbase + kg * 4;
#pragma unroll
    for (int j = 0; j < 4; ++j) {
        float ss = 0.f;
#pragma unroll
        for (int t = 0; t < 8; ++t) ss = fmaf(acc[t][j], acc[t][j], ss);
        ss += __shfl_xor(ss, 1);
        ss += __shfl_xor(ss, 2);
        ss += __shfl_xor(ss, 4);
        ss += __shfl_xor(ss, 8);
        float inv = 1.f / fmaxf(sqrtf(ss), 1e-12f);
#pragma unroll
        for (int t = 0; t < 8; ++t)
            Out[(orow + j) * 128 + 16 * t + r] = acc[t][j] * inv;
    }
}

// ---------------- launch ----------------

extern "C" void kernel_launch(void* const* d_in, const int* in_sizes, int n_in,
                              void* d_out, int out_size, void* d_ws, size_t ws_size,
                              hipStream_t stream) {
    const float* x       = (const float*)d_in[0];
    const int*   pos_idx = (const int*)d_in[1];
    const float* pos_w   = (const float*)d_in[2];
    const int*   neg_idx = (const int*)d_in[3];
    const float* neg_w   = (const float*)d_in[4];
    const float* W_org   = (const float*)d_in[5];
    const float* W_pos   = (const float*)d_in[6];
    const float* W_neg   = (const float*)d_in[7];
    const float* g_org   = (const float*)d_in[8];
    const float* b_org   = (const float*)d_in[9];
    const float* g_pos   = (const float*)d_in[10];
    const float* b_pos   = (const float*)d_in[11];
    const float* g_neg   = (const float*)d_in[12];
    const float* b_neg   = (const float*)d_in[13];
    const float* prelu_w = (const float*)d_in[14];
    const float* W_mlp   = (const float*)d_in[15];
    float* out = (float*)d_out;

    char* ws = (char*)d_ws;
    const size_t FB = (size_t)NNODES * 128 * 2;        // 10,240,000 B per feature buffer
    ushort* org0b = (ushort*)(ws);
    ushort* p0b   = (ushort*)(ws + FB);
    ushort* n0b   = (ushort*)(ws + 2 * FB);
    int2* edges   = (int2*)(ws + 3 * FB);              // 14,080,000 B
    char* small   = ws + 3 * FB + 14080000;
    int* ecnt     = (int*)small;                       // 5000 -> pad 5120
    float* sums   = (float*)(small + 5120);            // 1536
    float* sumsq  = (float*)(small + 5120 + 1536);     // 1536 (memset 0..8192)
    float* bn     = (float*)(small + 8192);            // 3072
    int2* rp2     = (int2*)(small + 8192 + 3072);      // 640,000
    ushort* Wb    = (ushort*)(small + 8192 + 3072 + 640000);   // 196,608 B
    uint* t1_pos  = (uint*)d_out;                      // blocked bf16 scratch halves of d_out
    uint* t1_neg  = (uint*)d_out + 4 * QSZU;

    hipMemsetAsync(small, 0, 8192, stream);

    partition_k<<<79, 256, 0, stream>>>(pos_idx, pos_w, neg_idx, neg_w, ecnt, edges);
    bucket_csr_k<<<2 * NBUCK, 256, 0, stream>>>(ecnt, edges, rp2);
    pack_all_k<<<384, 256, 0, stream>>>(W_org, W_pos, W_neg, W_mlp, Wb);

    mfma_gemm3_k<<<625, 256, 0, stream>>>(x, Wb, Wb + 16384, Wb + 32768,
                                          org0b, p0b, n0b, sums, sumsq);

    // Jacobi (a=b=1, K=3): x1 = 2*A@x0 ; x2 = 1.875*A@x1 - 1.6875*x0
    spmmq_k<1><<<40000, 256, 0, stream>>>(rp2, edges,
        (const uint*)p0b, (const uint*)n0b, nullptr, nullptr, t1_pos, t1_neg);
    spmmq_k<2><<<40000, 256, 0, stream>>>(rp2, edges,
        t1_pos, t1_neg, (const uint*)p0b, (const uint*)n0b, (uint*)p0b, (uint*)n0b);

    stats2_k<<<626, 256, 0, stream>>>(p0b, n0b, sums, sumsq);
    bnfin_k<<<1, 384, 0, stream>>>(sums, sumsq, g_org, b_org, g_pos, b_pos, g_neg, b_neg, bn);
    mfma_gemm_mlp_k<<<625, 256, 0, stream>>>(org0b, p0b, n0b, bn, prelu_w, Wb + 49152, out);

    (void)in_sizes; (void)n_in; (void)out_size; (void)ws_size;
}